// Round 1
// baseline (559.510 us; speedup 1.0000x reference)
//
#include <hip/hip_runtime.h>

#define HH 512
#define WW 512
#define NB 32
#define EPSF 1e-7f
#define DTF 0.05f

// zero-padded load within one (HH,WW) plane
__device__ __forceinline__ float ldz(const float* __restrict__ p, int i, int j) {
    return ((unsigned)i < (unsigned)HH && (unsigned)j < (unsigned)WW) ? p[i * WW + j] : 0.f;
}

// e4 = (sobel_x^2 + sobel_y^2)^2 at (i,j), zero-padded img
__device__ __forceinline__ float e4_at(const float* __restrict__ im, int i, int j) {
    float a = ldz(im, i - 1, j - 1), b = ldz(im, i - 1, j), c = ldz(im, i - 1, j + 1);
    float d = ldz(im, i,     j - 1),                        e = ldz(im, i,     j + 1);
    float f = ldz(im, i + 1, j - 1), g = ldz(im, i + 1, j), h = ldz(im, i + 1, j + 1);
    float ex = (a - c) + 2.f * (d - e) + (f - h);
    float ey = (a - f) + 2.f * (b - g) + (c - h);
    float s = ex * ex + ey * ey;
    return s * s;
}

// ---------------- Pass 1: global max of e4 ----------------
__global__ __launch_bounds__(256)
void max_e4_kernel(const float* __restrict__ img, unsigned int* __restrict__ wsmax) {
    int idx = blockIdx.x * 256 + threadIdx.x;
    int b = idx >> 18;          // / (512*512)
    int r = idx & 262143;
    int i = r >> 9;
    int j = r & 511;
    const float* im = img + (size_t)b * (HH * WW);
    float v = e4_at(im, i, j);

    // wave64 reduce
    for (int off = 32; off > 0; off >>= 1)
        v = fmaxf(v, __shfl_down(v, off, 64));

    __shared__ float smax[4];
    int lane = threadIdx.x & 63, wid = threadIdx.x >> 6;
    if (lane == 0) smax[wid] = v;
    __syncthreads();
    if (threadIdx.x == 0) {
        float m = fmaxf(fmaxf(smax[0], smax[1]), fmaxf(smax[2], smax[3]));
        // e4 >= 0: float bit pattern order == uint order
        atomicMax(wsmax, __float_as_uint(m));
    }
}

// ---------------- Pass 2: fully fused forcing function ----------------
__global__ __launch_bounds__(256)
void fused_ff(const float* __restrict__ u, const float* __restrict__ img,
              const float* __restrict__ pa, const float* __restrict__ pb,
              const float* __restrict__ pg,
              const unsigned int* __restrict__ wsmax,
              float* __restrict__ out) {
    const int j = blockIdx.x * 256 + threadIdx.x;
    const int i = blockIdx.y;
    const int b = blockIdx.z;
    if (j >= WW) return;
    const size_t base = (size_t)b * (HH * WW);
    const float* __restrict__ U  = u + base;
    const float* __restrict__ IM = img + base;

    const float M     = __uint_as_float(*wsmax);
    const float alpha = pa[0], beta = pb[0], gamma = pg[0];

    // edges = M/(e4+M) at center + 4-cross; out-of-range edges contribute 0
    // to the outer central-difference conv (SAME zero padding).
    const float ec = M * __builtin_amdgcn_rcpf(e4_at(IM, i, j) + M);
    const float el = (j > 0)      ? M * __builtin_amdgcn_rcpf(e4_at(IM, i, j - 1) + M) : 0.f;
    const float er = (j < WW - 1) ? M * __builtin_amdgcn_rcpf(e4_at(IM, i, j + 1) + M) : 0.f;
    const float et = (i > 0)      ? M * __builtin_amdgcn_rcpf(e4_at(IM, i - 1, j) + M) : 0.f;
    const float eb = (i < HH - 1) ? M * __builtin_amdgcn_rcpf(e4_at(IM, i + 1, j) + M) : 0.f;
    const float gex = er - el;
    const float gey = et - eb;

    // u neighborhood (13 loads, zero-padded)
    const float uc = ldz(U, i, j);
    const float l1 = ldz(U, i, j - 1), r1 = ldz(U, i, j + 1);
    const float l2 = ldz(U, i, j - 2), r2 = ldz(U, i, j + 2);
    const float t1 = ldz(U, i - 1, j), b1 = ldz(U, i + 1, j);
    const float t2 = ldz(U, i - 2, j), b2 = ldz(U, i + 2, j);
    const float tl = ldz(U, i - 1, j - 1), tr = ldz(U, i - 1, j + 1);
    const float bl = ldz(U, i + 1, j - 1), br = ldz(U, i + 1, j + 1);

    // upwind transport
    const float xp = r1 - uc, xn = uc - l1;
    const float yp = t1 - uc, yn = uc - b1;
    const float fxp = fmaxf(gex, 0.f), fxn = fminf(gex, 0.f);
    const float fyp = fmaxf(gey, 0.f), fyn = fminf(gey, 0.f);
    const float transport = 20.f * ((fxp * xp + fxn * xn) + (fyp * yp + fyn * yn));

    // curvature: kappa = d/dx(px) + d/dy(py), px=gux/(n+eps), py=guy/(n+eps)
    const float gxc = r1 - l1, gyc = t1 - b1;
    const float nc = sqrtf(gxc * gxc + gyc * gyc + EPSF);

    float px_r = 0.f, px_l = 0.f, py_t = 0.f, py_b = 0.f;
    if (j < WW - 1) {  // (i, j+1)
        float gx = r2 - uc, gy = tr - br;
        float n = sqrtf(gx * gx + gy * gy + EPSF);
        px_r = gx * __builtin_amdgcn_rcpf(n + EPSF);
    }
    if (j > 0) {       // (i, j-1)
        float gx = uc - l2, gy = tl - bl;
        float n = sqrtf(gx * gx + gy * gy + EPSF);
        px_l = gx * __builtin_amdgcn_rcpf(n + EPSF);
    }
    if (i > 0) {       // (i-1, j)
        float gx = tr - tl, gy = t2 - uc;
        float n = sqrtf(gx * gx + gy * gy + EPSF);
        py_t = gy * __builtin_amdgcn_rcpf(n + EPSF);
    }
    if (i < HH - 1) {  // (i+1, j)
        float gx = br - bl, gy = uc - b2;
        float n = sqrtf(gx * gx + gy * gy + EPSF);
        py_b = gy * __builtin_amdgcn_rcpf(n + EPSF);
    }
    const float kappa = (px_r - px_l) + (py_t - py_b);

    const float curvature = ec * kappa * nc;
    const float balloon   = ec * nc;

    out[base + i * WW + j] = uc + DTF * (curvature * alpha + transport * beta + balloon * gamma);
}

extern "C" void kernel_launch(void* const* d_in, const int* in_sizes, int n_in,
                              void* d_out, int out_size, void* d_ws, size_t ws_size,
                              hipStream_t stream) {
    const float* u   = (const float*)d_in[0];
    const float* img = (const float*)d_in[1];
    const float* pa  = (const float*)d_in[2];
    const float* pb  = (const float*)d_in[3];
    const float* pg  = (const float*)d_in[4];
    float* out = (float*)d_out;
    unsigned int* wsmax = (unsigned int*)d_ws;

    // d_ws is re-poisoned 0xAA before every launch — must zero the max slot.
    hipMemsetAsync(wsmax, 0, sizeof(unsigned int), stream);

    const int total = NB * HH * WW;
    max_e4_kernel<<<total / 256, 256, 0, stream>>>(img, wsmax);

    dim3 grid(WW / 256, HH, NB);
    fused_ff<<<grid, 256, 0, stream>>>(u, img, pa, pb, pg, wsmax, out);
}

// Round 2
// 254.951 us; speedup vs baseline: 2.1946x; 2.1946x over previous
//
#include <hip/hip_runtime.h>

#define HH 512
#define WW 512
#define NB 32
#define EPSF 1e-7f
#define DTF 0.05f
#define RSTRIP 8   // output rows per block in pass 2

// zero-padded load within one (HH,WW) plane
__device__ __forceinline__ float ldz(const float* __restrict__ p, int i, int j) {
    return ((unsigned)i < (unsigned)HH && (unsigned)j < (unsigned)WW) ? p[i * WW + j] : 0.f;
}

// e4 = (sobel_x^2 + sobel_y^2)^2 at (i,j), zero-padded img
__device__ __forceinline__ float e4_at(const float* __restrict__ im, int i, int j) {
    float a = ldz(im, i - 1, j - 1), b = ldz(im, i - 1, j), c = ldz(im, i - 1, j + 1);
    float d = ldz(im, i,     j - 1),                        e = ldz(im, i,     j + 1);
    float f = ldz(im, i + 1, j - 1), g = ldz(im, i + 1, j), h = ldz(im, i + 1, j + 1);
    float ex = (a - c) + 2.f * (d - e) + (f - h);
    float ey = (a - f) + 2.f * (b - g) + (c - h);
    float s = ex * ex + ey * ey;
    return s * s;
}

// ---------------- Pass 1: global max of e4 ----------------
// 256 blocks x 256 threads, grid-stride: 256 same-address atomics total
// (previous version: 32768 atomics -> 375us of pure serialization).
__global__ __launch_bounds__(256)
void max_e4_kernel(const float* __restrict__ img, unsigned int* __restrict__ wsmax) {
    const int total = NB * HH * WW;
    const int stride = 256 * 256;
    float v = 0.f;
    for (int idx = blockIdx.x * 256 + threadIdx.x; idx < total; idx += stride) {
        int b = idx >> 18;
        int r = idx & (HH * WW - 1);
        int i = r >> 9;
        int j = r & (WW - 1);
        v = fmaxf(v, e4_at(img + (size_t)b * (HH * WW), i, j));
    }
    // wave64 reduce
    for (int off = 32; off > 0; off >>= 1)
        v = fmaxf(v, __shfl_down(v, off, 64));
    __shared__ float smax[4];
    int lane = threadIdx.x & 63, wid = threadIdx.x >> 6;
    if (lane == 0) smax[wid] = v;
    __syncthreads();
    if (threadIdx.x == 0) {
        float m = fmaxf(fmaxf(smax[0], smax[1]), fmaxf(smax[2], smax[3]));
        atomicMax(wsmax, __float_as_uint(m));  // e4 >= 0: uint order == float order
    }
}

// ---------------- Pass 2: strip-tiled fused forcing function ----------------
// Block = 256 threads, strip = full width x RSTRIP rows. edges/px/py computed
// ONCE per point into LDS (strip + 1-row halo), then consumed.
__global__ __launch_bounds__(256)
void fused_ff(const float* __restrict__ u, const float* __restrict__ img,
              const float* __restrict__ pa, const float* __restrict__ pb,
              const float* __restrict__ pg,
              const unsigned int* __restrict__ wsmax,
              float* __restrict__ out) {
    const int s = blockIdx.y;     // strip index, i0 = s*RSTRIP
    const int b = blockIdx.z;
    const int i0 = s * RSTRIP;
    const size_t base = (size_t)b * (HH * WW);
    const float* __restrict__ U  = u + base;
    const float* __restrict__ IM = img + base;

    __shared__ float sE [RSTRIP + 2][WW];
    __shared__ float sPX[RSTRIP + 2][WW];
    __shared__ float sPY[RSTRIP + 2][WW];

    const float M     = __uint_as_float(*wsmax);
    const float alpha = pa[0], beta = pb[0], gamma = pg[0];

    // Phase 1: edges + px + py for rows i0-1 .. i0+RSTRIP (zero for out-of-plane rows)
    for (int t = threadIdx.x; t < (RSTRIP + 2) * WW; t += 256) {
        const int rr = t >> 9;          // 0 .. RSTRIP+1
        const int j  = t & (WW - 1);
        const int i  = i0 - 1 + rr;
        float e = 0.f, px = 0.f, py = 0.f;
        if ((unsigned)i < (unsigned)HH) {
            e = M * __builtin_amdgcn_rcpf(e4_at(IM, i, j) + M);
            const float gux = ldz(U, i, j + 1) - ldz(U, i, j - 1);
            const float guy = ldz(U, i - 1, j) - ldz(U, i + 1, j);
            const float n   = sqrtf(gux * gux + guy * guy + EPSF);
            const float rn  = __builtin_amdgcn_rcpf(n + EPSF);
            px = gux * rn;
            py = guy * rn;
        }
        sE [rr][j] = e;
        sPX[rr][j] = px;
        sPY[rr][j] = py;
    }
    __syncthreads();

    // Phase 2: outputs for rows i0 .. i0+RSTRIP-1
    for (int t = threadIdx.x; t < RSTRIP * WW; t += 256) {
        const int rr = t >> 9;
        const int j  = t & (WW - 1);
        const int i  = i0 + rr;
        const int li = rr + 1;          // LDS row of (i)

        const float ec  = sE[li][j];
        const float el  = (j > 0)      ? sE[li][j - 1] : 0.f;
        const float er  = (j < WW - 1) ? sE[li][j + 1] : 0.f;
        const float gex = er - el;
        const float gey = sE[li - 1][j] - sE[li + 1][j];

        const float uc = U[i * WW + j];
        const float l1 = ldz(U, i, j - 1), r1 = ldz(U, i, j + 1);
        const float t1 = ldz(U, i - 1, j), b1 = ldz(U, i + 1, j);

        // upwind transport
        const float xp = r1 - uc, xn = uc - l1;
        const float yp = t1 - uc, yn = uc - b1;
        const float transport = 20.f * ((fmaxf(gex, 0.f) * xp + fminf(gex, 0.f) * xn)
                                      + (fmaxf(gey, 0.f) * yp + fminf(gey, 0.f) * yn));

        // curvature
        const float gxc = r1 - l1, gyc = t1 - b1;
        const float nc  = sqrtf(gxc * gxc + gyc * gyc + EPSF);
        const float pxr = (j < WW - 1) ? sPX[li][j + 1] : 0.f;
        const float pxl = (j > 0)      ? sPX[li][j - 1] : 0.f;
        const float kappa = (pxr - pxl) + (sPY[li - 1][j] - sPY[li + 1][j]);

        out[base + i * WW + j] = uc + DTF * (ec * kappa * nc * alpha
                                           + transport * beta
                                           + ec * nc * gamma);
    }
}

extern "C" void kernel_launch(void* const* d_in, const int* in_sizes, int n_in,
                              void* d_out, int out_size, void* d_ws, size_t ws_size,
                              hipStream_t stream) {
    const float* u   = (const float*)d_in[0];
    const float* img = (const float*)d_in[1];
    const float* pa  = (const float*)d_in[2];
    const float* pb  = (const float*)d_in[3];
    const float* pg  = (const float*)d_in[4];
    float* out = (float*)d_out;
    unsigned int* wsmax = (unsigned int*)d_ws;

    // d_ws is re-poisoned 0xAA before every launch — must zero the max slot.
    hipMemsetAsync(wsmax, 0, sizeof(unsigned int), stream);

    max_e4_kernel<<<256, 256, 0, stream>>>(img, wsmax);

    dim3 grid(1, HH / RSTRIP, NB);
    fused_ff<<<grid, 256, 0, stream>>>(u, img, pa, pb, pg, wsmax, out);
}

// Round 3
// 171.603 us; speedup vs baseline: 3.2605x; 1.4857x over previous
//
#include <hip/hip_runtime.h>
#include <hip/hip_fp16.h>

#define HH 512
#define WW 512
#define NB 32
#define EPSF 1e-7f
#define DTF 0.05f
#define RSTRIP 8   // output rows per block in pass 2
#define RS1 32     // rows per block in pass 1

// zero-padded load within one (HH,WW) plane
__device__ __forceinline__ float ldz(const float* __restrict__ p, int i, int j) {
    return ((unsigned)i < (unsigned)HH && (unsigned)j < (unsigned)WW) ? p[i * WW + j] : 0.f;
}

// load 3 adjacent columns (j-1,j,j+1) of row i, zero-padded
__device__ __forceinline__ void row3(const float* __restrict__ im, int i, int j,
                                     float& m, float& c, float& p) {
    if ((unsigned)i < (unsigned)HH) {
        const float* r = im + i * WW;
        c = r[j];
        m = (j > 0)      ? r[j - 1] : 0.f;
        p = (j < WW - 1) ? r[j + 1] : 0.f;
    } else { m = c = p = 0.f; }
}

// ---------------- Pass 1: per-block partial max of e4 ----------------
// 1024 blocks (4/CU). Rolling 3-row window: 3 loads/px, no atomics.
__global__ __launch_bounds__(256)
void max_e4_kernel(const float* __restrict__ img, float* __restrict__ partial) {
    const int j  = blockIdx.x * 256 + threadIdx.x;
    const int i0 = blockIdx.y * RS1;
    const float* __restrict__ im = img + (size_t)blockIdx.z * (HH * WW);

    float am, ac, ap, bm, bc, bp, cm, cc, cp;
    row3(im, i0 - 1, j, am, ac, ap);
    row3(im, i0,     j, bm, bc, bp);
    float v = 0.f;
    #pragma unroll 4
    for (int i = i0; i < i0 + RS1; ++i) {
        row3(im, i + 1, j, cm, cc, cp);
        const float ex = (am - ap) + 2.f * (bm - bp) + (cm - cp);
        const float ey = (am - cm) + 2.f * (ac - cc) + (ap - cp);
        const float s2 = ex * ex + ey * ey;
        v = fmaxf(v, s2 * s2);
        am = bm; ac = bc; ap = bp;
        bm = cm; bc = cc; bp = cp;
    }
    // wave64 + block reduce
    for (int off = 32; off > 0; off >>= 1)
        v = fmaxf(v, __shfl_down(v, off, 64));
    __shared__ float smax[4];
    const int lane = threadIdx.x & 63, wid = threadIdx.x >> 6;
    if (lane == 0) smax[wid] = v;
    __syncthreads();
    if (threadIdx.x == 0) {
        partial[blockIdx.x + 2 * (blockIdx.y + 16 * blockIdx.z)] =
            fmaxf(fmaxf(smax[0], smax[1]), fmaxf(smax[2], smax[3]));
    }
}

// ---------------- Pass 1b: reduce 1024 partials -> M ----------------
__global__ __launch_bounds__(256)
void reduce_max(const float* __restrict__ partial, float* __restrict__ wsmax) {
    float v = fmaxf(fmaxf(partial[threadIdx.x],       partial[threadIdx.x + 256]),
                    fmaxf(partial[threadIdx.x + 512], partial[threadIdx.x + 768]));
    for (int off = 32; off > 0; off >>= 1)
        v = fmaxf(v, __shfl_down(v, off, 64));
    __shared__ float smax[4];
    const int lane = threadIdx.x & 63, wid = threadIdx.x >> 6;
    if (lane == 0) smax[wid] = v;
    __syncthreads();
    if (threadIdx.x == 0)
        wsmax[0] = fmaxf(fmaxf(smax[0], smax[1]), fmaxf(smax[2], smax[3]));
}

// ---------------- Pass 2: strip-tiled fused forcing function ----------------
// LDS halved vs R2 via fp16 edges + packed half2 (px,py): 30 KB -> 5 blocks/CU.
__global__ __launch_bounds__(256)
void fused_ff(const float* __restrict__ u, const float* __restrict__ img,
              const float* __restrict__ pa, const float* __restrict__ pb,
              const float* __restrict__ pg,
              const float* __restrict__ wsmax,
              float* __restrict__ out) {
    const int i0 = blockIdx.y * RSTRIP;
    const size_t base = (size_t)blockIdx.z * (HH * WW);
    const float* __restrict__ U  = u + base;
    const float* __restrict__ IM = img + base;

    __shared__ __half  sE[RSTRIP + 2][WW];   // edges
    __shared__ __half2 sP[RSTRIP + 2][WW];   // (px, py)

    const float M     = wsmax[0];
    const float alpha = pa[0], beta = pb[0], gamma = pg[0];

    // Phase 1: edges + px + py for rows i0-1 .. i0+RSTRIP
    for (int t = threadIdx.x; t < (RSTRIP + 2) * WW; t += 256) {
        const int rr = t >> 9;
        const int j  = t & (WW - 1);
        const int i  = i0 - 1 + rr;
        float e = 0.f, px = 0.f, py = 0.f;
        if ((unsigned)i < (unsigned)HH) {
            float ex, ey, gux, guy;
            if (i > 0 && i < HH - 1 && j > 0 && j < WW - 1) {
                // interior fast path: no bounds cndmasks
                const float* r0 = IM + (i - 1) * WW + j;
                const float* r1 = IM +  i      * WW + j;
                const float* r2 = IM + (i + 1) * WW + j;
                const float a = r0[-1], b2 = r0[0], c = r0[1];
                const float d = r1[-1],             e2 = r1[1];
                const float f = r2[-1], g = r2[0],  h = r2[1];
                ex = (a - c) + 2.f * (d - e2) + (f - h);
                ey = (a - f) + 2.f * (b2 - g) + (c - h);
                const float* u1 = U + i * WW + j;
                gux = u1[1] - u1[-1];
                guy = u1[-WW] - u1[WW];
            } else {
                const float a = ldz(IM, i - 1, j - 1), b2 = ldz(IM, i - 1, j), c = ldz(IM, i - 1, j + 1);
                const float d = ldz(IM, i,     j - 1),                         e2 = ldz(IM, i,     j + 1);
                const float f = ldz(IM, i + 1, j - 1), g = ldz(IM, i + 1, j),  h = ldz(IM, i + 1, j + 1);
                ex = (a - c) + 2.f * (d - e2) + (f - h);
                ey = (a - f) + 2.f * (b2 - g) + (c - h);
                gux = ldz(U, i, j + 1) - ldz(U, i, j - 1);
                guy = ldz(U, i - 1, j) - ldz(U, i + 1, j);
            }
            const float s2 = ex * ex + ey * ey;
            e = M * __builtin_amdgcn_rcpf(s2 * s2 + M);
            const float n  = sqrtf(gux * gux + guy * guy + EPSF);
            const float rn = __builtin_amdgcn_rcpf(n + EPSF);
            px = gux * rn;
            py = guy * rn;
        }
        sE[rr][j] = __float2half(e);
        sP[rr][j] = __floats2half2_rn(px, py);
    }
    __syncthreads();

    // Phase 2: outputs for rows i0 .. i0+RSTRIP-1
    for (int t = threadIdx.x; t < RSTRIP * WW; t += 256) {
        const int rr = t >> 9;
        const int j  = t & (WW - 1);
        const int i  = i0 + rr;
        const int li = rr + 1;

        const float ec  = __half2float(sE[li][j]);
        const float el  = (j > 0)      ? __half2float(sE[li][j - 1]) : 0.f;
        const float er  = (j < WW - 1) ? __half2float(sE[li][j + 1]) : 0.f;
        const float gex = er - el;
        const float gey = __half2float(sE[li - 1][j]) - __half2float(sE[li + 1][j]);

        float uc, l1, r1, t1, b1;
        if (i > 0 && i < HH - 1 && j > 0 && j < WW - 1) {
            const float* u1 = U + i * WW + j;
            uc = u1[0]; l1 = u1[-1]; r1 = u1[1]; t1 = u1[-WW]; b1 = u1[WW];
        } else {
            uc = ldz(U, i, j);
            l1 = ldz(U, i, j - 1); r1 = ldz(U, i, j + 1);
            t1 = ldz(U, i - 1, j); b1 = ldz(U, i + 1, j);
        }

        // upwind transport
        const float xp = r1 - uc, xn = uc - l1;
        const float yp = t1 - uc, yn = uc - b1;
        const float transport = 20.f * ((fmaxf(gex, 0.f) * xp + fminf(gex, 0.f) * xn)
                                      + (fmaxf(gey, 0.f) * yp + fminf(gey, 0.f) * yn));

        // curvature
        const float gxc = r1 - l1, gyc = t1 - b1;
        const float nc  = sqrtf(gxc * gxc + gyc * gyc + EPSF);
        const float pxr = (j < WW - 1) ? __low2float(sP[li][j + 1]) : 0.f;
        const float pxl = (j > 0)      ? __low2float(sP[li][j - 1]) : 0.f;
        const float kappa = (pxr - pxl)
                          + (__high2float(sP[li - 1][j]) - __high2float(sP[li + 1][j]));

        out[base + i * WW + j] = uc + DTF * (ec * kappa * nc * alpha
                                           + transport * beta
                                           + ec * nc * gamma);
    }
}

extern "C" void kernel_launch(void* const* d_in, const int* in_sizes, int n_in,
                              void* d_out, int out_size, void* d_ws, size_t ws_size,
                              hipStream_t stream) {
    const float* u   = (const float*)d_in[0];
    const float* img = (const float*)d_in[1];
    const float* pa  = (const float*)d_in[2];
    const float* pb  = (const float*)d_in[3];
    const float* pg  = (const float*)d_in[4];
    float* out = (float*)d_out;
    float* partial = (float*)d_ws;        // 1024 floats, all written unconditionally
    float* wsmax   = partial + 1024;      // final max

    dim3 g1(WW / 256, HH / RS1, NB);      // 2 x 16 x 32 = 1024 blocks
    max_e4_kernel<<<g1, 256, 0, stream>>>(img, partial);
    reduce_max<<<1, 256, 0, stream>>>(partial, wsmax);

    dim3 g2(1, HH / RSTRIP, NB);
    fused_ff<<<g2, 256, 0, stream>>>(u, img, pa, pb, pg, wsmax, out);
}

// Round 4
// 133.577 us; speedup vs baseline: 4.1887x; 1.2847x over previous
//
#include <hip/hip_runtime.h>

#define HH 512
#define WW 512
#define NB 32
#define EPSF 1e-7f
#define DTF 0.05f
#define RS1 32     // rows per block in pass 1
#define RSF 16     // output rows per wave in fused pass
#define CSW 62     // output columns per wave (64 lanes - 2 halo)
#define NCS 9      // ceil(512/62) column strips

// ---------------- Pass 1 (unchanged from R3: known good) ----------------
__device__ __forceinline__ float ldz(const float* __restrict__ p, int i, int j) {
    return ((unsigned)i < (unsigned)HH && (unsigned)j < (unsigned)WW) ? p[i * WW + j] : 0.f;
}
__device__ __forceinline__ void row3(const float* __restrict__ im, int i, int j,
                                     float& m, float& c, float& p) {
    if ((unsigned)i < (unsigned)HH) {
        const float* r = im + i * WW;
        c = r[j];
        m = (j > 0)      ? r[j - 1] : 0.f;
        p = (j < WW - 1) ? r[j + 1] : 0.f;
    } else { m = c = p = 0.f; }
}

__global__ __launch_bounds__(256)
void max_e4_kernel(const float* __restrict__ img, float* __restrict__ partial) {
    const int j  = blockIdx.x * 256 + threadIdx.x;
    const int i0 = blockIdx.y * RS1;
    const float* __restrict__ im = img + (size_t)blockIdx.z * (HH * WW);
    float am, ac, ap, bm, bc, bp, cm, cc, cp;
    row3(im, i0 - 1, j, am, ac, ap);
    row3(im, i0,     j, bm, bc, bp);
    float v = 0.f;
    #pragma unroll 4
    for (int i = i0; i < i0 + RS1; ++i) {
        row3(im, i + 1, j, cm, cc, cp);
        const float ex = (am - ap) + 2.f * (bm - bp) + (cm - cp);
        const float ey = (am - cm) + 2.f * (ac - cc) + (ap - cp);
        const float s2 = ex * ex + ey * ey;
        v = fmaxf(v, s2 * s2);
        am = bm; ac = bc; ap = bp;
        bm = cm; bc = cc; bp = cp;
    }
    for (int off = 32; off > 0; off >>= 1)
        v = fmaxf(v, __shfl_down(v, off, 64));
    __shared__ float smax[4];
    const int lane = threadIdx.x & 63, wid = threadIdx.x >> 6;
    if (lane == 0) smax[wid] = v;
    __syncthreads();
    if (threadIdx.x == 0)
        partial[blockIdx.x + 2 * (blockIdx.y + 16 * blockIdx.z)] =
            fmaxf(fmaxf(smax[0], smax[1]), fmaxf(smax[2], smax[3]));
}

__global__ __launch_bounds__(256)
void reduce_max(const float* __restrict__ partial, float* __restrict__ wsmax) {
    float v = fmaxf(fmaxf(partial[threadIdx.x],       partial[threadIdx.x + 256]),
                    fmaxf(partial[threadIdx.x + 512], partial[threadIdx.x + 768]));
    for (int off = 32; off > 0; off >>= 1)
        v = fmaxf(v, __shfl_down(v, off, 64));
    __shared__ float smax[4];
    const int lane = threadIdx.x & 63, wid = threadIdx.x >> 6;
    if (lane == 0) smax[wid] = v;
    __syncthreads();
    if (threadIdx.x == 0)
        wsmax[0] = fmaxf(fmaxf(smax[0], smax[1]), fmaxf(smax[2], smax[3]));
}

// ---------------- Pass 2: column-rolling wave-autonomous stencil ----------------
__device__ __forceinline__ float bperm(int addr, float v) {
    return __int_as_float(__builtin_amdgcn_ds_bpermute(addr, __float_as_int(v)));
}

template<bool EDGE>
__device__ __forceinline__ void ld3(const float* __restrict__ row,
                                    int jm, int jj, int jp,
                                    bool fm, bool fc, bool fp2,
                                    float& m, float& c, float& p) {
    if (EDGE) {
        m = fm  ? row[jm] : 0.f;
        c = fc  ? row[jj] : 0.f;
        p = fp2 ? row[jp] : 0.f;
    } else {
        m = row[jj - 1]; c = row[jj]; p = row[jj + 1];
    }
}

template<bool EDGE>
__device__ __forceinline__ void ff_wave(const float* __restrict__ U,
                                        const float* __restrict__ IM,
                                        float* __restrict__ O,
                                        int o0, int j, int lane, float M,
                                        float dta, float dtb, float dtg) {
    const int  jj  = EDGE ? min(max(j, 0), WW - 1)     : j;
    const int  jm  = EDGE ? min(max(j - 1, 0), WW - 1) : 0;
    const int  jp  = EDGE ? min(max(j + 1, 0), WW - 1) : 0;
    const bool fm  = (unsigned)(j - 1) < (unsigned)WW;
    const bool fc  = (unsigned)j       < (unsigned)WW;
    const bool fp2 = (unsigned)(j + 1) < (unsigned)WW;
    const bool do_store = (lane >= 1) && (lane <= 62) && fc;
    const int  bpu = ((lane + 63) & 63) << 2;   // pull from lane-1
    const int  bpd = ((lane + 1)  & 63) << 2;   // pull from lane+1

    // rolling state: img rows o,o+1 ; u rows o-1(center),o,o+1 ; e/px/py history
    float I0m = 0, I0c = 0, I0p = 0, I1m = 0, I1c = 0, I1p = 0;
    float R0c = 0, R1m = 0, R1c = 0, R1p = 0, R2m = 0, R2c = 0, R2p = 0;
    float e1 = 0, e2 = 0, px2 = 0, py1 = 0, py2 = 0;

    if (o0 >= 2) {   // uniform: preload rows o0-2, o0-1
        ld3<EDGE>(IM + (o0 - 2) * WW, jm, jj, jp, fm, fc, fp2, I0m, I0c, I0p);
        ld3<EDGE>(U  + (o0 - 2) * WW, jm, jj, jp, fm, fc, fp2, R1m, R1c, R1p);
        ld3<EDGE>(IM + (o0 - 1) * WW, jm, jj, jp, fm, fc, fp2, I1m, I1c, I1p);
        ld3<EDGE>(U  + (o0 - 1) * WW, jm, jj, fp2 ? jp : jp, fm, fc, fp2, R2m, R2c, R2p);
    }

    #pragma unroll 6
    for (int o = o0 - 2; o < o0 + RSF; ++o) {
        const int t = o + 2;
        float nm, ncn, npn, wm, wc, wp;
        if (t <= HH - 1) {
            ld3<EDGE>(IM + t * WW, jm, jj, jp, fm, fc, fp2, nm, ncn, npn);
            ld3<EDGE>(U  + t * WW, jm, jj, jp, fm, fc, fp2, wm, wc, wp);
        } else { nm = ncn = npn = wm = wc = wp = 0.f; }

        // edges / px / py at row o+1 (img rows o,o+1,o+2 ; u rows o..o+2)
        float ex = (I0m - I0p) + 2.f * (I1m - I1p) + (nm - npn);
        float ey = (I0m - nm) + 2.f * (I0c - ncn) + (I0p - npn);
        float s2 = ex * ex + ey * ey;
        float eN = M * __builtin_amdgcn_rcpf(s2 * s2 + M);
        float gux = R2p - R2m;
        float guy = R1c - wc;
        float rn  = __builtin_amdgcn_rsqf(gux * gux + guy * guy + EPSF);
        float pxN = gux * rn;
        float pyN = guy * rn;
        if (EDGE && !fc) { eN = 0.f; pxN = 0.f; pyN = 0.f; }      // column outside plane
        if (o < -1 || o >= HH - 1) { eN = 0.f; pxN = 0.f; pyN = 0.f; }  // row o+1 outside

        if (o >= o0) {   // emit output row o
            float el  = bperm(bpu, e2),  er  = bperm(bpd, e2);
            float pxl = bperm(bpu, px2), pxr = bperm(bpd, px2);
            float gex = er - el;
            float gey = e1 - eN;
            float xp = R1p - R1c, xn = R1c - R1m;
            float yp = R0c - R1c, yn = R1c - R2c;
            float transport = (fmaxf(gex, 0.f) * xp + fminf(gex, 0.f) * xn)
                            + (fmaxf(gey, 0.f) * yp + fminf(gey, 0.f) * yn);
            float gxc = R1p - R1m, gyc = R0c - R2c;
            float ncv = __builtin_amdgcn_sqrtf(gxc * gxc + gyc * gyc + EPSF);
            float kappa = (pxr - pxl) + (py1 - pyN);
            float val = R1c + e2 * ncv * (kappa * dta + dtg) + transport * dtb;
            if (do_store) O[o * WW + j] = val;
        }
        // roll
        I0m = I1m; I0c = I1c; I0p = I1p; I1m = nm; I1c = ncn; I1p = npn;
        R0c = R1c; R1m = R2m; R1c = R2c; R1p = R2p; R2m = wm; R2c = wc; R2p = wp;
        e1 = e2; e2 = eN; px2 = pxN; py1 = py2; py2 = pyN;
    }
}

__global__ __launch_bounds__(256)
void fused_ff(const float* __restrict__ u, const float* __restrict__ img,
              const float* __restrict__ pa, const float* __restrict__ pb,
              const float* __restrict__ pg, const float* __restrict__ wsmax,
              float* __restrict__ out) {
    const int wid  = blockIdx.x * 4 + (threadIdx.x >> 6);
    const int lane = threadIdx.x & 63;
    const int cs = wid % NCS;
    const int t1 = wid / NCS;
    const int rs = t1 & 31;            // 512/RSF = 32 row strips
    const int b  = t1 >> 5;
    const int j  = cs * CSW + lane - 1;
    const int o0 = rs * RSF;
    const size_t base = (size_t)b * (HH * WW);

    const float M   = wsmax[0];
    const float dta = DTF * pa[0];
    const float dtb = 20.f * DTF * pb[0];
    const float dtg = DTF * pg[0];

    if (cs == 0 || cs == NCS - 1)
        ff_wave<true >(u + base, img + base, out + base, o0, j, lane, M, dta, dtb, dtg);
    else
        ff_wave<false>(u + base, img + base, out + base, o0, j, lane, M, dta, dtb, dtg);
}

extern "C" void kernel_launch(void* const* d_in, const int* in_sizes, int n_in,
                              void* d_out, int out_size, void* d_ws, size_t ws_size,
                              hipStream_t stream) {
    const float* u   = (const float*)d_in[0];
    const float* img = (const float*)d_in[1];
    const float* pa  = (const float*)d_in[2];
    const float* pb  = (const float*)d_in[3];
    const float* pg  = (const float*)d_in[4];
    float* out = (float*)d_out;
    float* partial = (float*)d_ws;        // 1024 floats, all written unconditionally
    float* wsmax   = partial + 1024;

    dim3 g1(WW / 256, HH / RS1, NB);      // 2 x 16 x 32 = 1024 blocks
    max_e4_kernel<<<g1, 256, 0, stream>>>(img, partial);
    reduce_max<<<1, 256, 0, stream>>>(partial, wsmax);

    // 9 col-strips x 32 row-strips x 32 batch = 9216 waves = 2304 blocks of 4 waves
    const int nblocks = (NCS * (HH / RSF) * NB) / 4;
    fused_ff<<<nblocks, 256, 0, stream>>>(u, img, pa, pb, pg, wsmax, out);
}

// Round 5
// 124.980 us; speedup vs baseline: 4.4768x; 1.0688x over previous
//
#include <hip/hip_runtime.h>

#define HH 512
#define WW 512
#define NB 32
#define EPSF 1e-7f
#define DTF 0.05f
#define RS1 8      // rows per wave, pass 1
#define RSF 8      // output rows per wave, pass 2

// lane-to-lane pull via LDS-pipe permute (no LDS storage)
__device__ __forceinline__ float bperm(int addr, float v) {
    return __int_as_float(__builtin_amdgcn_ds_bpermute(addr, __float_as_int(v)));
}

// One image row, 8 cols/lane + 2 halo cols from neighbor lanes.
// v[1..8] = cols 8*lane .. 8*lane+7 ; v[0] = col-1 ; v[9] = col+8.
// Lanes 0/63 outer halos are true image borders -> zero-pad free.
struct R10 { float v[10]; };

__device__ __forceinline__ void load_row10(const float* __restrict__ base, int row,
                                           int lane, int bpu, int bpd,
                                           bool lo, bool hi, R10& r) {
    if ((unsigned)row < (unsigned)HH) {               // wave-uniform branch
        const float4* p = (const float4*)(base + row * WW + 8 * lane);
        float4 a = p[0], b = p[1];
        r.v[1] = a.x; r.v[2] = a.y; r.v[3] = a.z; r.v[4] = a.w;
        r.v[5] = b.x; r.v[6] = b.y; r.v[7] = b.z; r.v[8] = b.w;
    } else {
        #pragma unroll
        for (int k = 1; k <= 8; ++k) r.v[k] = 0.f;
    }
    float l = bperm(bpu, r.v[8]);   // lane-1's col 8l-1
    float h = bperm(bpd, r.v[1]);   // lane+1's col 8l+8
    r.v[0] = lo ? 0.f : l;
    r.v[9] = hi ? 0.f : h;
}

// ---------------- Pass 1: partial max of e4, wave-per-row-strip ----------------
__global__ __launch_bounds__(256, 2)
void max_e4_kernel(const float* __restrict__ img, float* __restrict__ partial) {
    const int wid  = blockIdx.x * 4 + (threadIdx.x >> 6);
    const int lane = threadIdx.x & 63;
    const int rs = wid & 63;                 // 64 strips of RS1 rows
    const int b  = wid >> 6;
    const int i0 = rs * RS1;
    const float* __restrict__ IM = img + (size_t)b * (HH * WW);
    const bool lo = (lane == 0), hi = (lane == 63);
    const int bpu = ((lane + 63) & 63) << 2, bpd = ((lane + 1) & 63) << 2;

    R10 A, B, C;
    load_row10(IM, i0 - 1, lane, bpu, bpd, lo, hi, A);
    load_row10(IM, i0,     lane, bpu, bpd, lo, hi, B);
    float m = 0.f;
    #pragma unroll
    for (int i = i0; i < i0 + RS1; ++i) {
        load_row10(IM, i + 1, lane, bpu, bpd, lo, hi, C);
        #pragma unroll
        for (int k = 1; k <= 8; ++k) {
            float ex = (A.v[k-1] - A.v[k+1]) + 2.f * (B.v[k-1] - B.v[k+1]) + (C.v[k-1] - C.v[k+1]);
            float ey = (A.v[k-1] - C.v[k-1]) + 2.f * (A.v[k] - C.v[k]) + (A.v[k+1] - C.v[k+1]);
            float s2 = ex * ex + ey * ey;
            m = fmaxf(m, s2 * s2);
        }
        A = B; B = C;
    }
    for (int off = 32; off > 0; off >>= 1)
        m = fmaxf(m, __shfl_down(m, off, 64));
    if (lane == 0) partial[wid] = m;         // 2048 partials, all written
}

// ---------------- Pass 1b: 2048 partials -> M ----------------
__global__ __launch_bounds__(256)
void reduce_max(const float* __restrict__ partial, float* __restrict__ wsmax) {
    float v = 0.f;
    #pragma unroll
    for (int k = 0; k < 8; ++k)
        v = fmaxf(v, partial[threadIdx.x + 256 * k]);
    for (int off = 32; off > 0; off >>= 1)
        v = fmaxf(v, __shfl_down(v, off, 64));
    __shared__ float smax[4];
    const int lane = threadIdx.x & 63, w = threadIdx.x >> 6;
    if (lane == 0) smax[w] = v;
    __syncthreads();
    if (threadIdx.x == 0)
        wsmax[0] = fmaxf(fmaxf(smax[0], smax[1]), fmaxf(smax[2], smax[3]));
}

// ---------------- Pass 2: wave-per-full-row fused forcing function ----------------
__global__ __launch_bounds__(256, 2)
void fused_ff(const float* __restrict__ u, const float* __restrict__ img,
              const float* __restrict__ pa, const float* __restrict__ pb,
              const float* __restrict__ pg, const float* __restrict__ wsmax,
              float* __restrict__ out) {
    const int wid  = blockIdx.x * 4 + (threadIdx.x >> 6);
    const int lane = threadIdx.x & 63;
    const int rs = wid & 63;                 // 64 strips of RSF rows
    const int b  = wid >> 6;
    const int o0 = rs * RSF;
    const size_t base = (size_t)b * (HH * WW);
    const float* __restrict__ U  = u + base;
    const float* __restrict__ IM = img + base;
    float* __restrict__ O = out + base;
    const bool lo = (lane == 0), hi = (lane == 63);
    const int bpu = ((lane + 63) & 63) << 2, bpd = ((lane + 1) & 63) << 2;

    const float M   = wsmax[0];
    const float dta = DTF * pa[0];
    const float dtb = 20.f * DTF * pb[0];
    const float dtg = DTF * pg[0];

    // rolling state (all registers): img rows o,o+1 ; u rows o-1..o+1 ; e/px/py history
    R10 I0 = {}, I1 = {}, R1 = {}, R2 = {}, E2 = {}, PX2 = {};
    float R0[9] = {}, E1[9] = {}, PY1[9] = {}, PY2[9] = {};

    if (o0 >= 2) {   // wave-uniform preload of rows o0-2, o0-1
        load_row10(IM, o0 - 2, lane, bpu, bpd, lo, hi, I0);
        load_row10(IM, o0 - 1, lane, bpu, bpd, lo, hi, I1);
        load_row10(U,  o0 - 2, lane, bpu, bpd, lo, hi, R1);
        load_row10(U,  o0 - 1, lane, bpu, bpd, lo, hi, R2);
    }

    #pragma unroll
    for (int o = o0 - 2; o < o0 + RSF; ++o) {
        R10 C, W;
        load_row10(IM, o + 2, lane, bpu, bpd, lo, hi, C);
        load_row10(U,  o + 2, lane, bpu, bpd, lo, hi, W);

        // e / px / py at row o+1 (img rows o,o+1,o+2 ; u rows o..o+2)
        float eN[10], PXN[10], PYN[9];
        if (o >= -1 && o < HH - 1) {   // wave-uniform row validity
            #pragma unroll
            for (int k = 1; k <= 8; ++k) {
                float ex = (I0.v[k-1] - I0.v[k+1]) + 2.f * (I1.v[k-1] - I1.v[k+1]) + (C.v[k-1] - C.v[k+1]);
                float ey = (I0.v[k-1] - C.v[k-1]) + 2.f * (I0.v[k] - C.v[k]) + (I0.v[k+1] - C.v[k+1]);
                float s2 = ex * ex + ey * ey;
                eN[k] = M * __builtin_amdgcn_rcpf(s2 * s2 + M);
                float gux = R2.v[k+1] - R2.v[k-1];
                float guy = R1.v[k] - W.v[k];
                float rn  = __builtin_amdgcn_rsqf(gux * gux + guy * guy + EPSF);
                PXN[k] = gux * rn;
                PYN[k] = guy * rn;
            }
        } else {
            #pragma unroll
            for (int k = 1; k <= 8; ++k) { eN[k] = 0.f; PXN[k] = 0.f; PYN[k] = 0.f; }
        }
        {   // halos for eN / PXN (needed when they become centers)
            float a = bperm(bpu, eN[8]),  bb = bperm(bpd, eN[1]);
            float c = bperm(bpu, PXN[8]), d  = bperm(bpd, PXN[1]);
            eN[0]  = lo ? 0.f : a;  eN[9]  = hi ? 0.f : bb;
            PXN[0] = lo ? 0.f : c;  PXN[9] = hi ? 0.f : d;
        }

        if (o >= o0) {   // emit output row o
            float vals[8];
            #pragma unroll
            for (int k = 1; k <= 8; ++k) {
                float gex = E2.v[k+1] - E2.v[k-1];
                float gey = E1[k] - eN[k];
                float xp = R1.v[k+1] - R1.v[k], xn = R1.v[k] - R1.v[k-1];
                float yp = R0[k] - R1.v[k],     yn = R1.v[k] - R2.v[k];
                float tr = fmaxf(gex, 0.f) * xp + fminf(gex, 0.f) * xn
                         + fmaxf(gey, 0.f) * yp + fminf(gey, 0.f) * yn;
                float gxc = R1.v[k+1] - R1.v[k-1], gyc = R0[k] - R2.v[k];
                float ncv = __builtin_amdgcn_sqrtf(gxc * gxc + gyc * gyc + EPSF);
                float kap = (PX2.v[k+1] - PX2.v[k-1]) + (PY1[k] - PYN[k]);
                vals[k-1] = R1.v[k] + E2.v[k] * ncv * (kap * dta + dtg) + tr * dtb;
            }
            float4* p = (float4*)(O + o * WW + 8 * lane);
            p[0] = make_float4(vals[0], vals[1], vals[2], vals[3]);
            p[1] = make_float4(vals[4], vals[5], vals[6], vals[7]);
        }

        // roll
        I0 = I1; I1 = C;
        #pragma unroll
        for (int k = 1; k <= 8; ++k) { R0[k] = R1.v[k]; E1[k] = E2.v[k]; PY1[k] = PY2[k]; PY2[k] = PYN[k]; }
        R1 = R2; R2 = W;
        E2 = *(R10*)&eN[0]; PX2 = *(R10*)&PXN[0];
    }
}

extern "C" void kernel_launch(void* const* d_in, const int* in_sizes, int n_in,
                              void* d_out, int out_size, void* d_ws, size_t ws_size,
                              hipStream_t stream) {
    const float* u   = (const float*)d_in[0];
    const float* img = (const float*)d_in[1];
    const float* pa  = (const float*)d_in[2];
    const float* pb  = (const float*)d_in[3];
    const float* pg  = (const float*)d_in[4];
    float* out = (float*)d_out;
    float* partial = (float*)d_ws;        // 2048 floats, all written unconditionally
    float* wsmax   = partial + 2048;

    // 64 strips x 32 batch = 2048 waves = 512 blocks (2 blocks/CU)
    max_e4_kernel<<<512, 256, 0, stream>>>(img, partial);
    reduce_max<<<1, 256, 0, stream>>>(partial, wsmax);
    fused_ff<<<512, 256, 0, stream>>>(u, img, pa, pb, pg, wsmax, out);
}